// Round 6
// baseline (145.306 us; speedup 1.0000x reference)
//
#include <hip/hip_runtime.h>
#include <stdint.h>

#define S_ 512
#define B_ 32
#define D_ 256
#define XSZ ((int64_t)B_ * S_ * D_)

typedef __attribute__((ext_vector_type(8))) short bf16x8;
typedef __attribute__((ext_vector_type(4))) float f32x4;

#define WAITVMLG(n) asm volatile("s_waitcnt vmcnt(" #n ") lgkmcnt(0)" ::: "memory")
#define SCHEDB() __builtin_amdgcn_sched_barrier(0)
#define BAR() __builtin_amdgcn_s_barrier()

__device__ __forceinline__ unsigned short f2bf(float f) {
    union { float f; uint32_t u; } v; v.f = f;
    uint32_t r = v.u + 0x7FFFu + ((v.u >> 16) & 1u);
    return (unsigned short)(r >> 16);
}

__device__ __forceinline__ void gl_lds16(const unsigned short* g, void* lds_base) {
    __builtin_amdgcn_global_load_lds(
        (const __attribute__((address_space(1))) unsigned int*)g,
        (__attribute__((address_space(3))) unsigned int*)lds_base, 16, 0, 0);
}

__device__ __forceinline__ f32x4 MF(bf16x8 a, bf16x8 b, f32x4 c) {
    return __builtin_amdgcn_mfma_f32_16x16x32_bf16(a, b, c, 0, 0, 0);
}

// ---------- prep: xT transpose [0,1024) + W conversions [1024,1408) ----------
__global__ __launch_bounds__(256) void prep_kernel(
    const float* __restrict__ gcn, const float* __restrict__ W,
    const float* __restrict__ Wout,
    unsigned short* __restrict__ XbfT,
    unsigned short* __restrict__ Wbf, unsigned short* __restrict__ WoutBf)
{
    __shared__ unsigned short T[64 * 65];
    const int bx = blockIdx.x;
    const int tid = threadIdx.x;

    if (bx < 1024) {  // gcn [b][s][d] -> XbfT [b][d][s]
        const int s0 = (bx & 7) * 64, d0 = ((bx >> 3) & 3) * 64, b = bx >> 5;
        const int r = tid >> 2, seg = tid & 3;
        const float* src = gcn + ((int64_t)(b * S_ + s0 + r)) * D_ + d0 + seg * 16;
#pragma unroll
        for (int q = 0; q < 4; q++) {
            float4 v = ((const float4*)src)[q];
            unsigned short* t = &T[r * 65 + seg * 16 + q * 4];
            t[0] = f2bf(v.x); t[1] = f2bf(v.y); t[2] = f2bf(v.z); t[3] = f2bf(v.w);
        }
        __syncthreads();
        unsigned short tmp[16];
#pragma unroll
        for (int j = 0; j < 16; j++) tmp[j] = T[(seg * 16 + j) * 65 + r];
        unsigned short* dst = &XbfT[((int64_t)(b * D_ + d0 + r)) * S_ + s0 + seg * 16];
        ((uint4*)dst)[0] = ((uint4*)tmp)[0];
        ((uint4*)dst)[1] = ((uint4*)tmp)[1];
    } else {
        const int i = ((bx - 1024) * 256 + tid) * 4;
        {
            float4 v = *(const float4*)&W[i];
            uint2 p;
            p.x = (uint32_t)f2bf(v.x) | ((uint32_t)f2bf(v.y) << 16);
            p.y = (uint32_t)f2bf(v.z) | ((uint32_t)f2bf(v.w) << 16);
            *(uint2*)&Wbf[i] = p;
        }
        {
            float4 v = *(const float4*)&Wout[i];
            uint2 p;
            p.x = (uint32_t)f2bf(v.x) | ((uint32_t)f2bf(v.y) << 16);
            p.y = (uint32_t)f2bf(v.z) | ((uint32_t)f2bf(v.w) << 16);
            *(uint2*)&WoutBf[i] = p;
        }
    }
}

// ---------- layers (all 3 heads, one l): 768 blocks @ 3/CU, 4 waves, 64s x 256d ----------
// bmm: BK=32 x16 steps; A = adj f32 reg-staged (cvt + fold I + rowsum), B via gl_lds.
// mm2: Ps (32KB swizzled LDS) x W direct-from-global (2-deep prefetch, no barriers).
template<int L>
__global__ __launch_bounds__(256, 3) void layers_kernel(
    const float* __restrict__ adjF,           // [3][B][S][S] f32
    const unsigned short* __restrict__ XbfT,  // [B][D][S]
    unsigned short* __restrict__ yTh,         // [3][B][D][S]
    const unsigned short* __restrict__ Wbf,   // [6][D][D]
    const float* __restrict__ bvec,           // [6][D]
    float* __restrict__ dInv,                 // [3][B][S] (L0 writes, L1 reads)
    unsigned short* __restrict__ yAll)        // [6][B][S][D]
{
    __shared__ __align__(16) char smem[41216];
    // bufA dbuf: [0,4096),[4096,8192)   64 rows x 64B
    // bufB dbuf: [8192,24576),[24576,40960)   256 rows x 64B
    // Ps overlay [0,32768): 64 rows x 512B;  Dsh [40960,41216)
    float* Dsh = (float*)(smem + 40960);

    const int tid = threadIdx.x;
    const int w   = tid >> 6;
    const int l   = tid & 63;
    const int lm  = l & 15;
    const int g   = l >> 4;

    int flat = blockIdx.x;
    flat = (flat & 7) * 96 + (flat >> 3);     // XCD-chunked, bijective (768 = 8*96)
    const int h   = flat >> 8;
    const int rem = flat & 255;
    const int b   = rem >> 3;
    const int s0  = (rem & 7) * 64;

    const float* adjB = adjF + (((int64_t)h * B_ + b) * S_ + s0) * S_;
    const unsigned short* xTB = (L == 0) ? (XbfT + (int64_t)b * D_ * S_)
                                         : (yTh + ((int64_t)h * B_ + b) * D_ * S_);
    const unsigned short* Wl  = Wbf + (int64_t)(h * 2 + L) * D_ * D_;
    const float* bl           = bvec + (h * 2 + L) * D_;

    // A staging (reg-staged f32): thread = (row ar, chunk ac of 8 floats)
    const int ar = tid >> 2;
    const int ac = tid & 3;
    const int aLds = ar * 64 + (((ac ^ (ar & 3) ^ ((ar >> 2) & 3))) << 4);
    // B staging via gl_lds: per wave j: row = w*64 + j*16 + (l>>2), chunk l&3
    const int bsrc = (((l & 3) ^ ((l >> 2) & 3) ^ g)) * 8;  // pre-swizzled source col (elems)
    // fragment read chunk (same for A and B rows): swz(row) = (lm&3)^((lm>>2)&3)
    const int co = ((g ^ (lm & 3) ^ ((lm >> 2) & 3)) << 4);

    f32x4 acc[4][4];
#pragma unroll
    for (int i = 0; i < 4; i++)
#pragma unroll
        for (int j = 0; j < 4; j++) acc[i][j] = (f32x4){0.f, 0.f, 0.f, 0.f};

    float4 av0, av1;
    float rowsum = 0.f;

    auto loadA = [&](int t0) {  // 2 vm loads (issue FIRST so cvt's wait leaves B in flight)
        const float* src = adjB + (int64_t)ar * S_ + t0 + ac * 8;
        av0 = ((const float4*)src)[0];
        av1 = ((const float4*)src)[1];
    };
    auto stageB = [&](int t0, int cur) {  // 4 gl_lds per wave
        char* bB = smem + 8192 + cur * 16384;
#pragma unroll
        for (int j = 0; j < 4; j++)
            gl_lds16(&xTB[(int64_t)(w * 64 + j * 16 + (l >> 2)) * S_ + t0 + bsrc],
                     bB + w * 4096 + j * 1024);
    };
    auto cvtwrite = [&](int cur, int t0) {
        const int srow = s0 + ar;
        const int bc = t0 + ac * 8;
        float e0 = av0.x + ((srow == bc + 0) ? 1.f : 0.f);
        float e1 = av0.y + ((srow == bc + 1) ? 1.f : 0.f);
        float e2 = av0.z + ((srow == bc + 2) ? 1.f : 0.f);
        float e3 = av0.w + ((srow == bc + 3) ? 1.f : 0.f);
        float e4 = av1.x + ((srow == bc + 4) ? 1.f : 0.f);
        float e5 = av1.y + ((srow == bc + 5) ? 1.f : 0.f);
        float e6 = av1.z + ((srow == bc + 6) ? 1.f : 0.f);
        float e7 = av1.w + ((srow == bc + 7) ? 1.f : 0.f);
        if (L == 0) rowsum += e0 + e1 + e2 + e3 + e4 + e5 + e6 + e7;
        uint4 p;
        p.x = (uint32_t)f2bf(e0) | ((uint32_t)f2bf(e1) << 16);
        p.y = (uint32_t)f2bf(e2) | ((uint32_t)f2bf(e3) << 16);
        p.z = (uint32_t)f2bf(e4) | ((uint32_t)f2bf(e5) << 16);
        p.w = (uint32_t)f2bf(e6) | ((uint32_t)f2bf(e7) << 16);
        *(uint4*)(smem + cur * 4096 + aLds) = p;
    };
    auto compute = [&](int cur) {
        const char* bA = smem + cur * 4096;
        const char* bB = smem + 8192 + cur * 16384;
        bf16x8 aF[4];
#pragma unroll
        for (int mi = 0; mi < 4; mi++)
            aF[mi] = *(const bf16x8*)(bA + (mi * 16 + lm) * 64 + co);
        __builtin_amdgcn_s_setprio(1);
#pragma unroll
        for (int ni = 0; ni < 4; ni++) {
            bf16x8 bF = *(const bf16x8*)(bB + (w * 64 + ni * 16 + lm) * 64 + co);
#pragma unroll
            for (int mi = 0; mi < 4; mi++)
                acc[mi][ni] = MF(aF[mi], bF, acc[mi][ni]);
        }
        __builtin_amdgcn_s_setprio(0);
    };

    // ---- bmm: P = (A+I)x, 16 steps of BK=32 ----
    loadA(0);
    stageB(0, 0);
    cvtwrite(0, 0);                    // compiler waits av (vmcnt(4)); B(0) stays in flight
    for (int t = 0; t < 16; t++) {
        const int cur = t & 1;
        if (t < 15) {
            loadA((t + 1) * 32);       // 2 vm (oldest of the new batch)
            stageB((t + 1) * 32, cur ^ 1);  // 4 vm
            WAITVMLG(6);               // drains B(t) + my ds_write of A(t)
        } else {
            WAITVMLG(0);
        }
        SCHEDB(); BAR(); SCHEDB();
        compute(cur);
        if (t < 15) cvtwrite(cur ^ 1, (t + 1) * 32);
        SCHEDB(); BAR();
    }

    // ---- denom (L0): rowsum already includes +I's 1 ----
    if (L == 0) {
        float rs = rowsum;
        rs += __shfl_xor(rs, 1);
        rs += __shfl_xor(rs, 2);
        if (ac == 0) {
            float inv = 1.0f / rs;
            Dsh[ar] = inv;
            dInv[((int64_t)h * B_ + b) * S_ + s0 + ar] = inv;
        }
    }

    // ---- P -> Ps (bf16, 512B rows, XOR-swizzled by (row&7)<<4) ----
#pragma unroll
    for (int mi = 0; mi < 4; mi++)
#pragma unroll
        for (int ni = 0; ni < 4; ni++) {
            const int col2 = (w * 64 + ni * 16 + lm) * 2;
#pragma unroll
            for (int r = 0; r < 4; r++) {
                const int row = mi * 16 + g * 4 + r;
                *(unsigned short*)(smem + row * 512 + (col2 ^ ((row & 7) << 4))) =
                    f2bf(acc[mi][ni][r]);
            }
        }
    __syncthreads();

    // ---- mm2: Q = P @ W^T ; W frags direct from global, 2-deep prefetch ----
    f32x4 acc2[4][4];
#pragma unroll
    for (int i = 0; i < 4; i++)
#pragma unroll
        for (int j = 0; j < 4; j++) acc2[i][j] = (f32x4){0.f, 0.f, 0.f, 0.f};

    const unsigned short* wb0 = Wl + (w * 64 + 0 * 16 + lm) * D_ + g * 8;
    const unsigned short* wb1 = Wl + (w * 64 + 1 * 16 + lm) * D_ + g * 8;
    const unsigned short* wb2 = Wl + (w * 64 + 2 * 16 + lm) * D_ + g * 8;
    const unsigned short* wb3 = Wl + (w * 64 + 3 * 16 + lm) * D_ + g * 8;
    bf16x8 wv0[4], wv1[4];
    wv0[0] = *(const bf16x8*)(wb0); wv0[1] = *(const bf16x8*)(wb1);
    wv0[2] = *(const bf16x8*)(wb2); wv0[3] = *(const bf16x8*)(wb3);
    wv1[0] = *(const bf16x8*)(wb0 + 32); wv1[1] = *(const bf16x8*)(wb1 + 32);
    wv1[2] = *(const bf16x8*)(wb2 + 32); wv1[3] = *(const bf16x8*)(wb3 + 32);

#pragma unroll
    for (int kc = 0; kc < 8; kc++) {
        bf16x8 aF[4];
#pragma unroll
        for (int mi = 0; mi < 4; mi++)
            aF[mi] = *(const bf16x8*)(smem + (mi * 16 + lm) * 512 +
                                      ((kc * 64 + g * 16) ^ ((lm & 7) << 4)));
        __builtin_amdgcn_s_setprio(1);
#pragma unroll
        for (int ni = 0; ni < 4; ni++) {
            bf16x8 bF = (kc & 1) ? wv1[ni] : wv0[ni];
#pragma unroll
            for (int mi = 0; mi < 4; mi++)
                acc2[mi][ni] = MF(aF[mi], bF, acc2[mi][ni]);
        }
        __builtin_amdgcn_s_setprio(0);
        if (kc + 2 < 8) {
            const int off = (kc + 2) * 32;
            if (kc & 1) {
                wv1[0] = *(const bf16x8*)(wb0 + off); wv1[1] = *(const bf16x8*)(wb1 + off);
                wv1[2] = *(const bf16x8*)(wb2 + off); wv1[3] = *(const bf16x8*)(wb3 + off);
            } else {
                wv0[0] = *(const bf16x8*)(wb0 + off); wv0[1] = *(const bf16x8*)(wb1 + off);
                wv0[2] = *(const bf16x8*)(wb2 + off); wv0[3] = *(const bf16x8*)(wb3 + off);
            }
        }
    }
    __syncthreads();   // all Ps reads retired before overwrite

    // ---- epilogue: y = relu((Q + 2b) * dinv) -> Ps ----
    float dv[4][4];
#pragma unroll
    for (int mi = 0; mi < 4; mi++)
#pragma unroll
        for (int r = 0; r < 4; r++) {
            const int row = mi * 16 + g * 4 + r;
            dv[mi][r] = (L == 0) ? Dsh[row]
                                 : dInv[((int64_t)h * B_ + b) * S_ + s0 + row];
        }

#pragma unroll
    for (int ni = 0; ni < 4; ni++) {
        const int col2 = (w * 64 + ni * 16 + lm) * 2;
        const float bv = 2.0f * bl[w * 64 + ni * 16 + lm];
#pragma unroll
        for (int mi = 0; mi < 4; mi++)
#pragma unroll
            for (int r = 0; r < 4; r++) {
                const int row = mi * 16 + g * 4 + r;
                float v = (acc2[mi][ni][r] + bv) * dv[mi][r];
                v = v > 0.f ? v : 0.f;
                *(unsigned short*)(smem + row * 512 + (col2 ^ ((row & 7) << 4))) = f2bf(v);
            }
    }
    __syncthreads();

    // coalesced y store: thread = (row rr, quarter q), 128B
    {
        unsigned short* y = yAll + (int64_t)(h * 2 + L) * XSZ + ((int64_t)(b * S_ + s0)) * D_;
        const int rr = tid >> 2, q = tid & 3;
        uint4 tmp[8];
#pragma unroll
        for (int c = 0; c < 8; c++)
            tmp[c] = *(const uint4*)(smem + rr * 512 + (((q * 8 + c) << 4) ^ ((rr & 7) << 4)));
        uint4* dst = (uint4*)&y[rr * D_ + q * 64];
#pragma unroll
        for (int c = 0; c < 8; c++) dst[c] = tmp[c];
    }
    if (L == 0) {  // transposed yT for next layer's bmm B-operand
        unsigned short* yT = yTh + ((int64_t)h * B_ + b) * D_ * S_;
        const int e = tid;
        unsigned short tmp[64];
#pragma unroll
        for (int s = 0; s < 64; s++)
            tmp[s] = *(const unsigned short*)(smem + s * 512 + ((e * 2) ^ ((s & 7) << 4)));
        uint4* dst = (uint4*)&yT[(int64_t)e * S_ + s0];
#pragma unroll
        for (int q = 0; q < 8; q++) dst[q] = ((uint4*)tmp)[q];
    }
}

// ---------- final: 512 blocks @ 2/CU, 32s x 256e, BK=64 x24 steps ----------
__global__ __launch_bounds__(256, 2) void final_kernel(
    const unsigned short* __restrict__ yAll,
    const unsigned short* __restrict__ WoutBf,  // [256][1536]
    const float* __restrict__ gcn,
    const float* __restrict__ bout,
    float* __restrict__ out)
{
    __shared__ __align__(16) char smem[73728];

    const int tid = threadIdx.x;
    const int w   = tid >> 6;
    const int l   = tid & 63;
    const int lm  = l & 15;
    const int g   = l >> 4;

    int flat = blockIdx.x;
    flat = (flat & 7) * 64 + (flat >> 3);    // 512 = 8*64, bijective
    const int b  = flat >> 4;
    const int s0 = (flat & 15) * 32;

    const int srow8  = l >> 3;
    const int schunk = ((l & 7) ^ (l >> 3)) * 8;
    const unsigned short* yBase = yAll + (int64_t)(b * S_ + s0) * D_;

    auto stage = [&](int kc, int cur) {       // 9 gl_lds per wave
        char* bA = smem + cur * 4096;
        char* bB = smem + 8192 + cur * 32768;
        const int hl = kc >> 2;
        const int e0 = (kc & 3) * 64;
        gl_lds16(&yBase[(int64_t)hl * XSZ + (w * 8 + srow8) * D_ + e0 + schunk],
                 bA + w * 1024);
#pragma unroll
        for (int j = 0; j < 8; j++)
            gl_lds16(&WoutBf[(w * 64 + j * 8 + srow8) * 1536 + kc * 64 + schunk],
                     bB + w * 8192 + j * 1024);
    };

    f32x4 acc[2][4];
#pragma unroll
    for (int i = 0; i < 2; i++)
#pragma unroll
        for (int j = 0; j < 4; j++) acc[i][j] = (f32x4){0.f, 0.f, 0.f, 0.f};

    stage(0, 0);
    for (int t = 0; t < 24; t++) {
        const int cur = t & 1;
        if (t < 23) { stage(t + 1, cur ^ 1); asm volatile("s_waitcnt vmcnt(9) lgkmcnt(0)" ::: "memory"); }
        else        { WAITVMLG(0); }
        SCHEDB(); BAR(); SCHEDB();
        {
            const char* bA = smem + cur * 4096;
            const char* bB = smem + 8192 + cur * 32768;
            __builtin_amdgcn_s_setprio(1);
#pragma unroll
            for (int h2 = 0; h2 < 2; h2++) {
                const int co = (((h2 * 4 + g) ^ (lm & 7)) << 4);
                bf16x8 a0 = *(const bf16x8*)(bA + lm * 128 + co);
                bf16x8 a1 = *(const bf16x8*)(bA + (16 + lm) * 128 + co);
#pragma unroll
                for (int ni = 0; ni < 4; ni++) {
                    bf16x8 bF = *(const bf16x8*)(bB + (w * 64 + ni * 16 + lm) * 128 + co);
                    acc[0][ni] = MF(a0, bF, acc[0][ni]);
                    acc[1][ni] = MF(a1, bF, acc[1][ni]);
                }
            }
            __builtin_amdgcn_s_setprio(0);
        }
        SCHEDB(); BAR();
    }

#pragma unroll
    for (int ni = 0; ni < 4; ni++) {
        const int e = w * 64 + ni * 16 + lm;
        const float bo = bout[e];
#pragma unroll
        for (int mi = 0; mi < 2; mi++)
#pragma unroll
            for (int r = 0; r < 4; r++) {
                const int row = mi * 16 + g * 4 + r;
                const int64_t idx = ((int64_t)(b * S_ + s0 + row)) * D_ + e;
                out[idx] = acc[mi][ni][r] + gcn[idx] + bo;
            }
    }
}

extern "C" void kernel_launch(void* const* d_in, const int* in_sizes, int n_in,
                              void* d_out, int out_size, void* d_ws, size_t ws_size,
                              hipStream_t stream) {
    const float* adj  = (const float*)d_in[0];
    const float* gcn  = (const float*)d_in[1];
    const float* W    = (const float*)d_in[4];
    const float* bvec = (const float*)d_in[5];
    const float* Wout = (const float*)d_in[6];
    const float* bout = (const float*)d_in[7];
    float* out = (float*)d_out;

    unsigned short* XbfT   = (unsigned short*)d_ws;
    unsigned short* yAll   = XbfT + XSZ;        // 6 slices [B][S][D]
    unsigned short* yTh    = yAll + 6 * XSZ;    // 3 slices [B][D][S]
    unsigned short* Wbf    = yTh + 3 * XSZ;
    unsigned short* WoutBf = Wbf + 6 * D_ * D_;
    float* dInv            = (float*)(WoutBf + 6 * D_ * D_);  // [3][B][S]

    prep_kernel<<<1408, 256, 0, stream>>>(gcn, W, Wout, XbfT, Wbf, WoutBf);
    layers_kernel<0><<<768, 256, 0, stream>>>(adj, XbfT, yTh, Wbf, bvec, dInv, yAll);
    layers_kernel<1><<<768, 256, 0, stream>>>(adj, XbfT, yTh, Wbf, bvec, dInv, yAll);
    final_kernel<<<512, 256, 0, stream>>>(yAll, WoutBf, gcn, bout, out);
}

// Round 7
// 136.118 us; speedup vs baseline: 1.0675x; 1.0675x over previous
//
#include <hip/hip_runtime.h>
#include <stdint.h>

#define S_ 512
#define B_ 32
#define D_ 256
#define XSZ ((int64_t)B_ * S_ * D_)

typedef __attribute__((ext_vector_type(8))) short bf16x8;
typedef __attribute__((ext_vector_type(4))) float f32x4;

#define WAITVMLG(n) asm volatile("s_waitcnt vmcnt(" #n ") lgkmcnt(0)" ::: "memory")
#define SCHEDB() __builtin_amdgcn_sched_barrier(0)
#define BAR() __builtin_amdgcn_s_barrier()

__device__ __forceinline__ unsigned short f2bf(float f) {
    union { float f; uint32_t u; } v; v.f = f;
    uint32_t r = v.u + 0x7FFFu + ((v.u >> 16) & 1u);
    return (unsigned short)(r >> 16);
}
__device__ __forceinline__ float bf2f(unsigned short h) {
    union { uint32_t u; float f; } v; v.u = ((uint32_t)h) << 16;
    return v.f;
}
__device__ __forceinline__ uint32_t pk2(float a, float b) {
    return (uint32_t)f2bf(a) | ((uint32_t)f2bf(b) << 16);
}

__device__ __forceinline__ void gl_lds16(const unsigned short* g, void* lds_base) {
    __builtin_amdgcn_global_load_lds(
        (const __attribute__((address_space(1))) unsigned int*)g,
        (__attribute__((address_space(3))) unsigned int*)lds_base, 16, 0, 0);
}

__device__ __forceinline__ f32x4 MF(bf16x8 a, bf16x8 b, f32x4 c) {
    return __builtin_amdgcn_mfma_f32_16x16x32_bf16(a, b, c, 0, 0, 0);
}

// ---------- prep: xT transpose [0,1024) + W conversions [1024,1408) ----------
__global__ __launch_bounds__(256) void prep_kernel(
    const float* __restrict__ gcn, const float* __restrict__ W,
    const float* __restrict__ Wout,
    unsigned short* __restrict__ XbfT,
    unsigned short* __restrict__ Wbf, unsigned short* __restrict__ WoutBf)
{
    __shared__ unsigned short T[64 * 65];
    const int bx = blockIdx.x;
    const int tid = threadIdx.x;

    if (bx < 1024) {  // gcn [b][s][d] -> XbfT [b][d][s]
        const int s0 = (bx & 7) * 64, d0 = ((bx >> 3) & 3) * 64, b = bx >> 5;
        const int r = tid >> 2, seg = tid & 3;
        const float* src = gcn + ((int64_t)(b * S_ + s0 + r)) * D_ + d0 + seg * 16;
#pragma unroll
        for (int q = 0; q < 4; q++) {
            float4 v = ((const float4*)src)[q];
            unsigned short* t = &T[r * 65 + seg * 16 + q * 4];
            t[0] = f2bf(v.x); t[1] = f2bf(v.y); t[2] = f2bf(v.z); t[3] = f2bf(v.w);
        }
        __syncthreads();
        unsigned short tmp[16];
#pragma unroll
        for (int j = 0; j < 16; j++) tmp[j] = T[(seg * 16 + j) * 65 + r];
        unsigned short* dst = &XbfT[((int64_t)(b * D_ + d0 + r)) * S_ + s0 + seg * 16];
        ((uint4*)dst)[0] = ((uint4*)tmp)[0];
        ((uint4*)dst)[1] = ((uint4*)tmp)[1];
    } else {
        const int i = ((bx - 1024) * 256 + tid) * 4;
        {
            float4 v = *(const float4*)&W[i];
            uint2 p; p.x = pk2(v.x, v.y); p.y = pk2(v.z, v.w);
            *(uint2*)&Wbf[i] = p;
        }
        {
            float4 v = *(const float4*)&Wout[i];
            uint2 p; p.x = pk2(v.x, v.y); p.y = pk2(v.z, v.w);
            *(uint2*)&WoutBf[i] = p;
        }
    }
}

// ---------- layers (all 3 heads, one l): 768 blocks @ 2/CU, 4 waves, 64s x 256d ----------
// bmm: BK=64 x8 steps; A = f32 adj reg-staged (cvt + swizzled ds_write, rowsum in L0),
//      B via 8 gl_lds. Counted vmcnt(12). Then +x, mm2 (LDS-staged W), epilogue.
template<int L>
__global__ __launch_bounds__(256, 2) void layers_kernel(
    const float* __restrict__ adjF,           // [3][B][S][S] f32
    const float* __restrict__ gcn,            // [B][S][D] f32 (L0 +x)
    const unsigned short* __restrict__ XbfT,  // [B][D][S]
    unsigned short* __restrict__ yTh,         // [3][B][D][S]
    const unsigned short* __restrict__ Wbf,   // [6][D][D]
    const float* __restrict__ bvec,           // [6][D]
    float* __restrict__ dInv,                 // [3][B][S] (L0 writes, L1 reads)
    unsigned short* __restrict__ yAll)        // [6][B][S][D]
{
    __shared__ __align__(16) char smem[81920];
    // bufA dbuf: [0,8192),[8192,16384)      64 rows x 128B
    // bufB dbuf: [16384,49152),[49152,81920) 256 rows x 128B
    // overlay after bmm: Ps [0,33792) (64 rows x 528B); Wst [36864,69632); Dsh [69632,69888)
    float* Dsh = (float*)(smem + 69632);

    const int tid = threadIdx.x;
    const int w   = tid >> 6;
    const int l   = tid & 63;
    const int lm  = l & 15;
    const int g   = l >> 4;

    int flat = blockIdx.x;
    flat = (flat & 7) * 96 + (flat >> 3);     // XCD-chunked, bijective (768 = 8*96)
    const int h   = flat >> 8;
    const int rem = flat & 255;
    const int b   = rem >> 3;
    const int s0  = (rem & 7) * 64;

    const float* adjB = adjF + (((int64_t)h * B_ + b) * S_ + s0) * S_;
    const unsigned short* xTB = (L == 0) ? (XbfT + (int64_t)b * D_ * S_)
                                         : (yTh + ((int64_t)h * B_ + b) * D_ * S_);
    const unsigned short* Wl  = Wbf + (int64_t)(h * 2 + L) * D_ * D_;
    const float* bl           = bvec + (h * 2 + L) * D_;

    // A staging: thread = (row ar, 16-float seg ac); 2 swizzled 16B chunks {2ac, 2ac+1}
    const int ar = tid >> 2;
    const int ac = tid & 3;
    // B staging (R5): srow8 = l>>3, schunk pre-swizzled source col
    const int srow8  = l >> 3;
    const int schunk = ((l & 7) ^ (l >> 3)) * 8;

    f32x4 acc[4][4];
#pragma unroll
    for (int i = 0; i < 4; i++)
#pragma unroll
        for (int j = 0; j < 4; j++) acc[i][j] = (f32x4){0.f, 0.f, 0.f, 0.f};

    float4 av0, av1, av2, av3;
    float rowsum = 0.f;

    auto loadA = [&](int t0) {  // 4 vm loads, issued FIRST each step
        const float* src = adjB + (int64_t)ar * S_ + t0 + ac * 16;
        av0 = ((const float4*)src)[0];
        av1 = ((const float4*)src)[1];
        av2 = ((const float4*)src)[2];
        av3 = ((const float4*)src)[3];
    };
    auto stageB = [&](int t0, int cur) {  // 8 gl_lds per wave
        char* bB = smem + 16384 + cur * 32768;
#pragma unroll
        for (int j = 0; j < 8; j++)
            gl_lds16(&xTB[(int64_t)(w * 64 + j * 8 + srow8) * S_ + t0 + schunk],
                     bB + w * 8192 + j * 1024);
    };
    auto cvtwrite = [&](int cur) {
        if (L == 0) {
            rowsum += av0.x + av0.y + av0.z + av0.w + av1.x + av1.y + av1.z + av1.w
                    + av2.x + av2.y + av2.z + av2.w + av3.x + av3.y + av3.z + av3.w;
        }
        uint4 p0, p1;
        p0.x = pk2(av0.x, av0.y); p0.y = pk2(av0.z, av0.w);
        p0.z = pk2(av1.x, av1.y); p0.w = pk2(av1.z, av1.w);
        p1.x = pk2(av2.x, av2.y); p1.y = pk2(av2.z, av2.w);
        p1.z = pk2(av3.x, av3.y); p1.w = pk2(av3.z, av3.w);
        char* bA = smem + cur * 8192;
        *(uint4*)(bA + ar * 128 + (((2 * ac)     ^ (ar & 7)) << 4)) = p0;
        *(uint4*)(bA + ar * 128 + (((2 * ac + 1) ^ (ar & 7)) << 4)) = p1;
    };
    auto compute = [&](int cur) {
        const char* bA = smem + cur * 8192;
        const char* bB = smem + 16384 + cur * 32768;
        __builtin_amdgcn_s_setprio(1);
#pragma unroll
        for (int h2 = 0; h2 < 2; h2++) {
            const int co = (((h2 * 4 + g) ^ (lm & 7)) << 4);
            bf16x8 aF[4];
#pragma unroll
            for (int mi = 0; mi < 4; mi++)
                aF[mi] = *(const bf16x8*)(bA + (mi * 16 + lm) * 128 + co);
#pragma unroll
            for (int ni = 0; ni < 4; ni++) {
                bf16x8 bF = *(const bf16x8*)(bB + (w * 64 + ni * 16 + lm) * 128 + co);
#pragma unroll
                for (int mi = 0; mi < 4; mi++)
                    acc[mi][ni] = MF(aF[mi], bF, acc[mi][ni]);
            }
        }
        __builtin_amdgcn_s_setprio(0);
    };

    // ---- bmm: P = A x, 8 steps of BK=64 ----
    loadA(0);
    stageB(0, 0);
    cvtwrite(0);                 // reg-use forces vmcnt(8): A(0) done, B(0) in flight
    for (int t = 0; t < 8; t++) {
        const int cur = t & 1;
        if (t < 7) {
            loadA((t + 1) * 64);            // +4 vm
            stageB((t + 1) * 64, cur ^ 1);  // +8 vm
            WAITVMLG(12);                   // drains B(t); A(t+1)+B(t+1) stay in flight
        } else {
            WAITVMLG(0);
        }
        SCHEDB(); BAR(); SCHEDB();
        compute(cur);
        if (t < 7) cvtwrite(cur ^ 1);       // waits A(t+1) (vmcnt 8), writes bufA
        SCHEDB(); BAR();
    }

    // ---- denom (L0): dInv = 1/(adj rowsum + 1) ----
    if (L == 0) {
        float rs = rowsum;
        rs += __shfl_xor(rs, 1);
        rs += __shfl_xor(rs, 2);
        if (ac == 0) {
            float inv = 1.0f / (rs + 1.0f);
            Dsh[ar] = inv;
            dInv[((int64_t)h * B_ + b) * S_ + s0 + ar] = inv;
        }
    }

    // ---- +x (Ax + outputs), then P -> Ps bf16 ----
    if (L == 0) {
        const float* xr = gcn + (int64_t)(b * S_ + s0) * D_;
#pragma unroll
        for (int mi = 0; mi < 4; mi++)
#pragma unroll
            for (int ni = 0; ni < 4; ni++) {
                const int col = w * 64 + ni * 16 + lm;
#pragma unroll
                for (int r = 0; r < 4; r++)
                    acc[mi][ni][r] += xr[(mi * 16 + g * 4 + r) * D_ + col];
            }
    } else {
        const unsigned short* xr = yAll + (int64_t)(h * 2) * XSZ + (int64_t)(b * S_ + s0) * D_;
#pragma unroll
        for (int mi = 0; mi < 4; mi++)
#pragma unroll
            for (int ni = 0; ni < 4; ni++) {
                const int col = w * 64 + ni * 16 + lm;
#pragma unroll
                for (int r = 0; r < 4; r++)
                    acc[mi][ni][r] += bf2f(xr[(mi * 16 + g * 4 + r) * D_ + col]);
            }
    }

    unsigned short* Ps = (unsigned short*)smem;
#pragma unroll
    for (int mi = 0; mi < 4; mi++)
#pragma unroll
        for (int ni = 0; ni < 4; ni++) {
            const int col = w * 64 + ni * 16 + lm;
#pragma unroll
            for (int r = 0; r < 4; r++)
                Ps[(mi * 16 + g * 4 + r) * 264 + col] = f2bf(acc[mi][ni][r]);
        }

    const int sr16 = l >> 2;
    const int sc4  = ((l & 3) ^ ((l >> 3) & 3)) * 8;
    auto stageW = [&](int kc, int cur) {         // 4 gl_lds per wave
        char* bW = smem + 36864 + cur * 16384;
#pragma unroll
        for (int j = 0; j < 4; j++)
            gl_lds16(&Wl[(w * 64 + j * 16 + sr16) * D_ + kc * 32 + sc4],
                     bW + w * 4096 + j * 1024);
    };
    stageW(0, 0);
    __syncthreads();

    // ---- mm2: Q = P @ W^T, 8 steps of BK=32 ----
    f32x4 acc2[4][4];
#pragma unroll
    for (int i = 0; i < 4; i++)
#pragma unroll
        for (int j = 0; j < 4; j++) acc2[i][j] = (f32x4){0.f, 0.f, 0.f, 0.f};

    for (int kc = 0; kc < 8; kc++) {
        const int cur = kc & 1;
        if (kc < 7) { stageW(kc + 1, cur ^ 1); WAITVMLG(4); }
        else        { WAITVMLG(0); }
        SCHEDB(); BAR(); SCHEDB();
        {
            const char* bW = smem + 36864 + cur * 16384;
            const int co2 = (g ^ ((lm >> 1) & 3)) << 4;
            bf16x8 aF[4];
#pragma unroll
            for (int mi = 0; mi < 4; mi++)
                aF[mi] = *(const bf16x8*)&Ps[(mi * 16 + lm) * 264 + kc * 32 + g * 8];
            __builtin_amdgcn_s_setprio(1);
#pragma unroll
            for (int ni = 0; ni < 4; ni++) {
                bf16x8 bF = *(const bf16x8*)(bW + (w * 64 + ni * 16 + lm) * 64 + co2);
#pragma unroll
                for (int mi = 0; mi < 4; mi++)
                    acc2[mi][ni] = MF(aF[mi], bF, acc2[mi][ni]);
            }
            __builtin_amdgcn_s_setprio(0);
        }
        SCHEDB(); BAR();
    }

    // ---- epilogue: y = relu((Q + 2b) * dInv) ----
    float dv[4][4];
#pragma unroll
    for (int mi = 0; mi < 4; mi++)
#pragma unroll
        for (int r = 0; r < 4; r++) {
            const int row = mi * 16 + g * 4 + r;
            dv[mi][r] = (L == 0) ? Dsh[row]
                                 : dInv[((int64_t)h * B_ + b) * S_ + s0 + row];
        }

#pragma unroll
    for (int ni = 0; ni < 4; ni++) {
        const int col = w * 64 + ni * 16 + lm;
        const float bv = 2.0f * bl[col];
#pragma unroll
        for (int mi = 0; mi < 4; mi++)
#pragma unroll
            for (int r = 0; r < 4; r++) {
                float v = (acc2[mi][ni][r] + bv) * dv[mi][r];
                v = v > 0.f ? v : 0.f;
                Ps[(mi * 16 + g * 4 + r) * 264 + col] = f2bf(v);
            }
    }
    __syncthreads();

    // coalesced y store: 64 rows x 512B, 128B/thread
    {
        unsigned short* y = yAll + (int64_t)(h * 2 + L) * XSZ + (int64_t)(b * S_ + s0) * D_;
        const int rr = tid >> 2, seg = (tid & 3) * 64;
        const uint4* srcp = (const uint4*)&Ps[rr * 264 + seg];
        uint4* dst = (uint4*)&y[rr * D_ + seg];
#pragma unroll
        for (int q = 0; q < 8; q++) dst[q] = srcp[q];
    }
    if (L == 0) {  // transposed yT for L1's bmm B-operand
        unsigned short* yT = yTh + ((int64_t)h * B_ + b) * D_ * S_;
        const int e = tid;
        unsigned short tmp[64];
#pragma unroll
        for (int s = 0; s < 64; s++) tmp[s] = Ps[s * 264 + e];
        uint4* dst = (uint4*)&yT[(int64_t)e * S_ + s0];
#pragma unroll
        for (int q = 0; q < 8; q++) dst[q] = ((uint4*)tmp)[q];
    }
}

// ---------- final: 256 blocks, tile 64s x 256e, K=1536 (24 steps of 64) ----------
__global__ __launch_bounds__(256, 2) void final_kernel(
    const unsigned short* __restrict__ yAll,
    const unsigned short* __restrict__ WoutBf,  // [256][1536]
    const float* __restrict__ gcn,
    const float* __restrict__ bout,
    float* __restrict__ out)
{
    __shared__ __align__(16) char smem[81920];

    const int tid = threadIdx.x;
    const int w   = tid >> 6;
    const int l   = tid & 63;
    const int lm  = l & 15;
    const int g   = l >> 4;

    int flat = blockIdx.x;
    flat = (flat & 7) * 32 + (flat >> 3);       // 256 = 8*32, bijective
    const int b  = flat >> 3;
    const int s0 = (flat & 7) * 64;

    const int srow8  = l >> 3;
    const int schunk = ((l & 7) ^ (l >> 3)) * 8;
    const unsigned short* yBase = yAll + (int64_t)(b * S_ + s0) * D_;

    auto stage = [&](int kc, int cur) {          // 10 gl_lds per wave
        char* bA = smem + cur * 8192;
        char* bB = smem + 16384 + cur * 32768;
        const int hl = kc >> 2;
        const int e0 = (kc & 3) * 64;
        gl_lds16(&yBase[(int64_t)hl * XSZ + (w * 16 + srow8) * D_ + e0 + schunk],
                 bA + w * 2048);
        gl_lds16(&yBase[(int64_t)hl * XSZ + (w * 16 + 8 + srow8) * D_ + e0 + schunk],
                 bA + w * 2048 + 1024);
#pragma unroll
        for (int j = 0; j < 8; j++)
            gl_lds16(&WoutBf[(w * 64 + j * 8 + srow8) * 1536 + kc * 64 + schunk],
                     bB + w * 8192 + j * 1024);
    };

    f32x4 acc[4][4];
#pragma unroll
    for (int i = 0; i < 4; i++)
#pragma unroll
        for (int j = 0; j < 4; j++) acc[i][j] = (f32x4){0.f, 0.f, 0.f, 0.f};

    stage(0, 0);
    for (int t = 0; t < 24; t++) {
        const int cur = t & 1;
        if (t < 23) { stage(t + 1, cur ^ 1); WAITVMLG(10); }
        else        { WAITVMLG(0); }
        SCHEDB(); BAR(); SCHEDB();
        {
            const char* bA = smem + cur * 8192;
            const char* bB = smem + 16384 + cur * 32768;
            __builtin_amdgcn_s_setprio(1);
#pragma unroll
            for (int h2 = 0; h2 < 2; h2++) {
                const int co = (((h2 * 4 + g) ^ (lm & 7)) << 4);
                bf16x8 aF[4];
#pragma unroll
                for (int mi = 0; mi < 4; mi++)
                    aF[mi] = *(const bf16x8*)(bA + (mi * 16 + lm) * 128 + co);
#pragma unroll
                for (int ni = 0; ni < 4; ni++) {
                    bf16x8 bF = *(const bf16x8*)(bB + (w * 64 + ni * 16 + lm) * 128 + co);
#pragma unroll
                    for (int mi = 0; mi < 4; mi++)
                        acc[mi][ni] = MF(aF[mi], bF, acc[mi][ni]);
                }
            }
            __builtin_amdgcn_s_setprio(0);
        }
        SCHEDB(); BAR();
    }

#pragma unroll
    for (int ni = 0; ni < 4; ni++) {
        const int e = w * 64 + ni * 16 + lm;
        const float bo = bout[e];
#pragma unroll
        for (int mi = 0; mi < 4; mi++)
#pragma unroll
            for (int r = 0; r < 4; r++) {
                const int row = mi * 16 + g * 4 + r;
                const int64_t idx = ((int64_t)(b * S_ + s0 + row)) * D_ + e;
                out[idx] = acc[mi][ni][r] + gcn[idx] + bo;
            }
    }
}

extern "C" void kernel_launch(void* const* d_in, const int* in_sizes, int n_in,
                              void* d_out, int out_size, void* d_ws, size_t ws_size,
                              hipStream_t stream) {
    const float* adj  = (const float*)d_in[0];
    const float* gcn  = (const float*)d_in[1];
    const float* W    = (const float*)d_in[4];
    const float* bvec = (const float*)d_in[5];
    const float* Wout = (const float*)d_in[6];
    const float* bout = (const float*)d_in[7];
    float* out = (float*)d_out;

    unsigned short* XbfT   = (unsigned short*)d_ws;
    unsigned short* yAll   = XbfT + XSZ;        // 6 slices [B][S][D]
    unsigned short* yTh    = yAll + 6 * XSZ;    // 3 slices [B][D][S]
    unsigned short* Wbf    = yTh + 3 * XSZ;
    unsigned short* WoutBf = Wbf + 6 * D_ * D_;
    float* dInv            = (float*)(WoutBf + 6 * D_ * D_);  // [3][B][S]

    prep_kernel<<<1408, 256, 0, stream>>>(gcn, W, Wout, XbfT, Wbf, WoutBf);
    layers_kernel<0><<<768, 256, 0, stream>>>(adj, gcn, XbfT, yTh, Wbf, bvec, dInv, yAll);
    layers_kernel<1><<<768, 256, 0, stream>>>(adj, gcn, XbfT, yTh, Wbf, bvec, dInv, yAll);
    final_kernel<<<256, 256, 0, stream>>>(yAll, WoutBf, gcn, bout, out);
}